// Round 9
// baseline (151.169 us; speedup 1.0000x reference)
//
#include <hip/hip_runtime.h>
#include <hip/hip_bf16.h>

typedef __bf16 bf16x8 __attribute__((ext_vector_type(8)));
typedef __bf16 bf16x2 __attribute__((ext_vector_type(2)));
typedef float f32x4 __attribute__((ext_vector_type(4)));

#define NROWS 8192
#define HALF_N 4096
#define DIM 128
#define ROW_BYTES 256            /* 128 bf16, plain row-major */
#define C1 14.42695040888963f    /* (1/T) * log2(e) */
#define LN2 0.6931471805599453f
#define GBLK 1024                /* 256 row-groups x 16 col-splits / 4 waves */

// ---- kernel 1: normalize (i,j) pairs -> rn, rnA(=rn*C1); p_k in f32 --------
// Pairing rows k and k+N in one block lets us compute the positive-pair
// cosine p_k exactly (f32) here, eliminating the separate rowloss kernel.
__global__ __launch_bounds__(256) void k_normalize(
    const float* __restrict__ zi, const float* __restrict__ zj,
    char* __restrict__ rn, char* __restrict__ rnA,
    float* __restrict__ rowsum, float* __restrict__ pbuf,
    unsigned int* __restrict__ done)
{
    const int wave = threadIdx.x >> 6;
    const int lane = threadIdx.x & 63;
    #pragma unroll
    for (int t = 0; t < 2; ++t) {
        const int idx = blockIdx.x * 8 + wave * 2 + t;   // i-row; partner idx+N
        float2 vi = *(const float2*)(zi + (size_t)idx * DIM + lane * 2);
        float2 vj = *(const float2*)(zj + (size_t)idx * DIM + lane * 2);
        float ssi = vi.x * vi.x + vi.y * vi.y;
        float ssj = vj.x * vj.x + vj.y * vj.y;
        float cr  = vi.x * vj.x + vi.y * vj.y;
        #pragma unroll
        for (int m = 32; m >= 1; m >>= 1) {
            ssi += __shfl_xor(ssi, m, 64);
            ssj += __shfl_xor(ssj, m, 64);
            cr  += __shfl_xor(cr,  m, 64);
        }
        const float sci = 1.0f / fmaxf(sqrtf(ssi), 1e-8f);
        const float scj = 1.0f / fmaxf(sqrtf(ssj), 1e-8f);
        bf16x2 a, b;
        a[0] = (__bf16)(vi.x * sci);      a[1] = (__bf16)(vi.y * sci);
        b[0] = (__bf16)(vi.x * sci * C1); b[1] = (__bf16)(vi.y * sci * C1);
        *(bf16x2*)(rn  + (size_t)idx * ROW_BYTES + lane * 4) = a;
        *(bf16x2*)(rnA + (size_t)idx * ROW_BYTES + lane * 4) = b;
        a[0] = (__bf16)(vj.x * scj);      a[1] = (__bf16)(vj.y * scj);
        b[0] = (__bf16)(vj.x * scj * C1); b[1] = (__bf16)(vj.y * scj * C1);
        *(bf16x2*)(rn  + (size_t)(idx + HALF_N) * ROW_BYTES + lane * 4) = a;
        *(bf16x2*)(rnA + (size_t)(idx + HALF_N) * ROW_BYTES + lane * 4) = b;
        if (lane == 0) {
            const float p = cr * sci * scj;
            pbuf[idx] = p;
            pbuf[idx + HALF_N] = p;
        }
    }
    if (threadIdx.x < 16) rowsum[blockIdx.x * 16 + threadIdx.x] = 0.0f;
    if (blockIdx.x == 0 && threadIdx.x == 0) *done = 0u;
}

// ---- kernel 2: wave-independent sim GEMM + exp rowsum + fused finalize -----
// Each wave: independent 32-row x 512-col strip. afrag (8 x bf16x8) in regs;
// B double-buffered in registers (explicit prefetch) so loads overlap
// MFMA+exp of the previous step. 1024 blocks = 4/CU = 4 waves/SIMD (the R8
// structure at 2 waves/SIMD was latency-exposed). No LDS, no barriers in the
// hot loop; compiler schedules vmcnt. Last block (done-counter, validated
// R3/R4) computes the final scalar loss.
__global__ __launch_bounds__(256) void k_gemm(
    const char* __restrict__ rn, const char* __restrict__ rnA,
    float* __restrict__ rowsum, const float* __restrict__ pbuf,
    unsigned int* __restrict__ done, float* __restrict__ out)
{
    const int wave = threadIdx.x >> 6;
    const int lane = threadIdx.x & 63;
    const int qrow = lane >> 4, lcol = lane & 15;
    const int cv = blockIdx.x & 15;                   // 16 col-splits of 512
    const int rg = (blockIdx.x >> 4) * 4 + wave;      // 256 row-groups of 32

    // A fragments: rows [rg*32,+32) from rnA (pre-scaled by C1), all K
    const char* Ab = rnA + (size_t)(rg * 32) * ROW_BYTES;
    bf16x8 afrag[2][4];
    #pragma unroll
    for (int mi = 0; mi < 2; ++mi)
        #pragma unroll
        for (int ks = 0; ks < 4; ++ks)
            afrag[mi][ks] = *(const bf16x8*)(Ab + (mi * 16 + lcol) * ROW_BYTES
                                             + ks * 64 + qrow * 16);

    float rsum[2][4];
    #pragma unroll
    for (int mi = 0; mi < 2; ++mi)
        #pragma unroll
        for (int r = 0; r < 4; ++r) rsum[mi][r] = 0.0f;

    const char* Bb = rn + (size_t)(cv * 512) * ROW_BYTES + lcol * ROW_BYTES + qrow * 16;

    bf16x8 b0[4], b1[4];
    #pragma unroll
    for (int ks = 0; ks < 4; ++ks) b0[ks] = *(const bf16x8*)(Bb + ks * 64);

    const f32x4 zero = {0.0f, 0.0f, 0.0f, 0.0f};
    #pragma unroll 1
    for (int s = 0; s < 32; s += 2) {                 // 2 steps of 16 cols each
        const char* bp1 = Bb + (size_t)(s + 1) * 16 * ROW_BYTES;
        #pragma unroll
        for (int ks = 0; ks < 4; ++ks) b1[ks] = *(const bf16x8*)(bp1 + ks * 64);

        f32x4 acc[2]; acc[0] = zero; acc[1] = zero;
        #pragma unroll
        for (int ks = 0; ks < 4; ++ks)
            #pragma unroll
            for (int mi = 0; mi < 2; ++mi)
                acc[mi] = __builtin_amdgcn_mfma_f32_16x16x32_bf16(
                    afrag[mi][ks], b0[ks], acc[mi], 0, 0, 0);
        #pragma unroll
        for (int mi = 0; mi < 2; ++mi)
            #pragma unroll
            for (int r = 0; r < 4; ++r)
                rsum[mi][r] += __builtin_amdgcn_exp2f(acc[mi][r]);

        if (s + 2 < 32) {
            const char* bp2 = Bb + (size_t)(s + 2) * 16 * ROW_BYTES;
            #pragma unroll
            for (int ks = 0; ks < 4; ++ks) b0[ks] = *(const bf16x8*)(bp2 + ks * 64);
        }

        acc[0] = zero; acc[1] = zero;
        #pragma unroll
        for (int ks = 0; ks < 4; ++ks)
            #pragma unroll
            for (int mi = 0; mi < 2; ++mi)
                acc[mi] = __builtin_amdgcn_mfma_f32_16x16x32_bf16(
                    afrag[mi][ks], b1[ks], acc[mi], 0, 0, 0);
        #pragma unroll
        for (int mi = 0; mi < 2; ++mi)
            #pragma unroll
            for (int r = 0; r < 4; ++r)
                rsum[mi][r] += __builtin_amdgcn_exp2f(acc[mi][r]);
    }

    // reduce over the 16 col-lanes, one atomic per row
    #pragma unroll
    for (int mi = 0; mi < 2; ++mi)
        #pragma unroll
        for (int r = 0; r < 4; ++r) {
            float v = rsum[mi][r];
            v += __shfl_xor(v, 1, 64);
            v += __shfl_xor(v, 2, 64);
            v += __shfl_xor(v, 4, 64);
            v += __shfl_xor(v, 8, 64);
            if (lcol == 0)
                atomicAdd(&rowsum[rg * 32 + mi * 16 + qrow * 4 + r], v);
        }

    // ---- last-block finalize (R3/R4-validated protocol) ----
    __syncthreads();
    __shared__ int is_last;
    if (threadIdx.x == 0) {
        __threadfence();
        unsigned old = __hip_atomic_fetch_add(done, 1u, __ATOMIC_ACQ_REL,
                                              __HIP_MEMORY_SCOPE_AGENT);
        is_last = (old == GBLK - 1);
    }
    __syncthreads();
    if (!is_last) return;
    __threadfence();

    // loss_k = (log2(rowsum_k + 2^(p*C1)) - p*C1) * ln2   [v_log_f32 is LOG2]
    float lsum = 0.0f;
    for (int r = threadIdx.x; r < NROWS; r += 256) {
        float rs = __hip_atomic_load(&rowsum[r], __ATOMIC_RELAXED, __HIP_MEMORY_SCOPE_AGENT);
        float pc = pbuf[r] * C1;
        float S  = rs + __builtin_amdgcn_exp2f(pc);
        lsum += (__builtin_amdgcn_logf(S) - pc) * LN2;
    }
    #pragma unroll
    for (int m = 32; m >= 1; m >>= 1) lsum += __shfl_xor(lsum, m, 64);
    __shared__ float part[4];
    if (lane == 0) part[wave] = lsum;
    __syncthreads();
    if (threadIdx.x == 0)
        out[0] = (part[0] + part[1] + part[2] + part[3]) * (1.0f / (float)NROWS);
}

extern "C" void kernel_launch(void* const* d_in, const int* in_sizes, int n_in,
                              void* d_out, int out_size, void* d_ws, size_t ws_size,
                              hipStream_t stream)
{
    const float* zi = (const float*)d_in[0];
    const float* zj = (const float*)d_in[1];
    float* out = (float*)d_out;

    // ws: rn 2MB | rnA 2MB | rowsum f32[8192] | pbuf f32[8192] | done
    char*  rn     = (char*)d_ws;
    char*  rnA    = rn + (size_t)NROWS * ROW_BYTES;
    float* rowsum = (float*)(rnA + (size_t)NROWS * ROW_BYTES);
    float* pbuf   = rowsum + NROWS;
    unsigned int* done = (unsigned int*)(pbuf + NROWS);

    k_normalize<<<NROWS / 16, 256, 0, stream>>>(zi, zj, rn, rnA, rowsum, pbuf, done);
    k_gemm<<<GBLK, 256, 0, stream>>>(rn, rnA, rowsum, pbuf, done, out);
}

// Round 10
// 136.672 us; speedup vs baseline: 1.1061x; 1.1061x over previous
//
#include <hip/hip_runtime.h>
#include <hip/hip_bf16.h>

typedef __bf16 bf16x8 __attribute__((ext_vector_type(8)));
typedef __bf16 bf16x2 __attribute__((ext_vector_type(2)));
typedef float f32x4 __attribute__((ext_vector_type(4)));

#define NROWS 8192
#define HALF_N 4096
#define DIM 128
#define ROW_BYTES 256            /* 128 bf16, plain row-major */
#define C1 14.42695040888963f    /* (1/T) * log2(e) */
#define LN2 0.6931471805599453f
#define GBLK 1024                /* 32 block-rows x 32 col-splits */

// ---- kernel 1: normalize (i,j) pairs -> rn, rnA(=rn*C1); p_k in f32 --------
__global__ __launch_bounds__(256) void k_normalize(
    const float* __restrict__ zi, const float* __restrict__ zj,
    char* __restrict__ rn, char* __restrict__ rnA,
    float* __restrict__ rowsum, float* __restrict__ pbuf,
    unsigned int* __restrict__ done)
{
    const int wave = threadIdx.x >> 6;
    const int lane = threadIdx.x & 63;
    #pragma unroll
    for (int t = 0; t < 2; ++t) {
        const int idx = blockIdx.x * 8 + wave * 2 + t;   // i-row; partner idx+N
        float2 vi = *(const float2*)(zi + (size_t)idx * DIM + lane * 2);
        float2 vj = *(const float2*)(zj + (size_t)idx * DIM + lane * 2);
        float ssi = vi.x * vi.x + vi.y * vi.y;
        float ssj = vj.x * vj.x + vj.y * vj.y;
        float cr  = vi.x * vj.x + vi.y * vj.y;
        #pragma unroll
        for (int m = 32; m >= 1; m >>= 1) {
            ssi += __shfl_xor(ssi, m, 64);
            ssj += __shfl_xor(ssj, m, 64);
            cr  += __shfl_xor(cr,  m, 64);
        }
        const float sci = 1.0f / fmaxf(sqrtf(ssi), 1e-8f);
        const float scj = 1.0f / fmaxf(sqrtf(ssj), 1e-8f);
        bf16x2 a, b;
        a[0] = (__bf16)(vi.x * sci);      a[1] = (__bf16)(vi.y * sci);
        b[0] = (__bf16)(vi.x * sci * C1); b[1] = (__bf16)(vi.y * sci * C1);
        *(bf16x2*)(rn  + (size_t)idx * ROW_BYTES + lane * 4) = a;
        *(bf16x2*)(rnA + (size_t)idx * ROW_BYTES + lane * 4) = b;
        a[0] = (__bf16)(vj.x * scj);      a[1] = (__bf16)(vj.y * scj);
        b[0] = (__bf16)(vj.x * scj * C1); b[1] = (__bf16)(vj.y * scj * C1);
        *(bf16x2*)(rn  + (size_t)(idx + HALF_N) * ROW_BYTES + lane * 4) = a;
        *(bf16x2*)(rnA + (size_t)(idx + HALF_N) * ROW_BYTES + lane * 4) = b;
        if (lane == 0) {
            const float p = cr * sci * scj;
            pbuf[idx] = p;
            pbuf[idx + HALF_N] = p;
        }
    }
    if (threadIdx.x < 16) rowsum[blockIdx.x * 16 + threadIdx.x] = 0.0f;
    if (blockIdx.x == 0 && threadIdx.x == 0) *done = 0u;
}

// ---- kernel 2: wave-independent sim GEMM + exp rowsum + fused finalize -----
// R8's PROVEN inner loop, verbatim: 64-row strip, afrag[4][4] (64 VGPR) held
// in regs, B loaded ONCE per 16-col step (single buffer, compiler schedules
// vmcnt). NO manual double-buffer (R9: VGPR demotion to 52, operand stalls,
// 2.5x regression). Only change vs R8: 32 col-splits of 256 -> 1024 blocks =
// 4 blocks/CU co-resident = 4 waves/SIMD of TLP to hide load/MFMA latency.
__global__ __launch_bounds__(256) void k_gemm(
    const char* __restrict__ rn, const char* __restrict__ rnA,
    float* __restrict__ rowsum, const float* __restrict__ pbuf,
    unsigned int* __restrict__ done, float* __restrict__ out)
{
    const int wave = threadIdx.x >> 6;
    const int lane = threadIdx.x & 63;
    const int qrow = lane >> 4, lcol = lane & 15;
    const int cv = blockIdx.x & 31;                   // 32 col-splits of 256
    const int rg = (blockIdx.x >> 5) * 4 + wave;      // 128 row-groups of 64

    // A fragments: rows [rg*64,+64) from rnA (pre-scaled by C1), all K
    const char* Ab = rnA + (size_t)(rg * 64) * ROW_BYTES;
    bf16x8 afrag[4][4];
    #pragma unroll
    for (int mi = 0; mi < 4; ++mi)
        #pragma unroll
        for (int ks = 0; ks < 4; ++ks)
            afrag[mi][ks] = *(const bf16x8*)(Ab + (mi * 16 + lcol) * ROW_BYTES
                                             + ks * 64 + qrow * 16);

    float rsum[4][4];
    #pragma unroll
    for (int mi = 0; mi < 4; ++mi)
        #pragma unroll
        for (int r = 0; r < 4; ++r) rsum[mi][r] = 0.0f;

    const char* Bb = rn + (size_t)(cv * 256) * ROW_BYTES + lcol * ROW_BYTES + qrow * 16;

    #pragma unroll 1
    for (int s = 0; s < 16; ++s) {                    // 16 steps of 16 cols
        const char* bp = Bb + (size_t)s * 16 * ROW_BYTES;
        bf16x8 bfrag[4];
        #pragma unroll
        for (int ks = 0; ks < 4; ++ks)
            bfrag[ks] = *(const bf16x8*)(bp + ks * 64);

        f32x4 acc[4];
        const f32x4 zero = {0.0f, 0.0f, 0.0f, 0.0f};
        #pragma unroll
        for (int mi = 0; mi < 4; ++mi) acc[mi] = zero;
        #pragma unroll
        for (int ks = 0; ks < 4; ++ks)
            #pragma unroll
            for (int mi = 0; mi < 4; ++mi)
                acc[mi] = __builtin_amdgcn_mfma_f32_16x16x32_bf16(
                    afrag[mi][ks], bfrag[ks], acc[mi], 0, 0, 0);

        // rowsum += 2^(s*C1); acc already holds s*C1 via pre-scaled A
        #pragma unroll
        for (int mi = 0; mi < 4; ++mi)
            #pragma unroll
            for (int r = 0; r < 4; ++r)
                rsum[mi][r] += __builtin_amdgcn_exp2f(acc[mi][r]);
    }

    // reduce over the 16 col-lanes, one atomic per row
    #pragma unroll
    for (int mi = 0; mi < 4; ++mi)
        #pragma unroll
        for (int r = 0; r < 4; ++r) {
            float v = rsum[mi][r];
            v += __shfl_xor(v, 1, 64);
            v += __shfl_xor(v, 2, 64);
            v += __shfl_xor(v, 4, 64);
            v += __shfl_xor(v, 8, 64);
            if (lcol == 0)
                atomicAdd(&rowsum[rg * 64 + mi * 16 + qrow * 4 + r], v);
        }

    // ---- last-block finalize (R3/R4/R9-validated protocol) ----
    __syncthreads();
    __shared__ int is_last;
    if (threadIdx.x == 0) {
        __threadfence();
        unsigned old = __hip_atomic_fetch_add(done, 1u, __ATOMIC_ACQ_REL,
                                              __HIP_MEMORY_SCOPE_AGENT);
        is_last = (old == GBLK - 1);
    }
    __syncthreads();
    if (!is_last) return;
    __threadfence();

    // loss_k = (log2(rowsum_k + 2^(p*C1)) - p*C1) * ln2   [v_log_f32 is LOG2]
    float lsum = 0.0f;
    for (int r = threadIdx.x; r < NROWS; r += 256) {
        float rs = __hip_atomic_load(&rowsum[r], __ATOMIC_RELAXED, __HIP_MEMORY_SCOPE_AGENT);
        float pc = pbuf[r] * C1;
        float S  = rs + __builtin_amdgcn_exp2f(pc);
        lsum += (__builtin_amdgcn_logf(S) - pc) * LN2;
    }
    #pragma unroll
    for (int m = 32; m >= 1; m >>= 1) lsum += __shfl_xor(lsum, m, 64);
    __shared__ float part[4];
    if (lane == 0) part[wave] = lsum;
    __syncthreads();
    if (threadIdx.x == 0)
        out[0] = (part[0] + part[1] + part[2] + part[3]) * (1.0f / (float)NROWS);
}

extern "C" void kernel_launch(void* const* d_in, const int* in_sizes, int n_in,
                              void* d_out, int out_size, void* d_ws, size_t ws_size,
                              hipStream_t stream)
{
    const float* zi = (const float*)d_in[0];
    const float* zj = (const float*)d_in[1];
    float* out = (float*)d_out;

    // ws: rn 2MB | rnA 2MB | rowsum f32[8192] | pbuf f32[8192] | done
    char*  rn     = (char*)d_ws;
    char*  rnA    = rn + (size_t)NROWS * ROW_BYTES;
    float* rowsum = (float*)(rnA + (size_t)NROWS * ROW_BYTES);
    float* pbuf   = rowsum + NROWS;
    unsigned int* done = (unsigned int*)(pbuf + NROWS);

    k_normalize<<<NROWS / 16, 256, 0, stream>>>(zi, zj, rn, rnA, rowsum, pbuf, done);
    k_gemm<<<GBLK, 256, 0, stream>>>(rn, rnA, rowsum, pbuf, done, out);
}

// Round 11
// 116.706 us; speedup vs baseline: 1.2953x; 1.1711x over previous
//
#include <hip/hip_runtime.h>
#include <hip/hip_bf16.h>

typedef __bf16 bf16x8 __attribute__((ext_vector_type(8)));
typedef __bf16 bf16x2 __attribute__((ext_vector_type(2)));
typedef float f32x4 __attribute__((ext_vector_type(4)));

#define NROWS 8192
#define HALF_N 4096
#define DIM 128
#define ROW_BYTES 256            /* 128 bf16, plain row-major */
#define C1 14.42695040888963f    /* (1/T) * log2(e) */
#define LN2 0.6931471805599453f
#define GBLK 1024                /* 32 block-row-groups x 32 col-splits */

// ---- kernel 1: normalize (i,j) pairs -> rn, rnA(=rn*C1); p_k in f32 --------
__global__ __launch_bounds__(256) void k_normalize(
    const float* __restrict__ zi, const float* __restrict__ zj,
    char* __restrict__ rn, char* __restrict__ rnA,
    float* __restrict__ rowsum, float* __restrict__ pbuf,
    unsigned int* __restrict__ done)
{
    const int wave = threadIdx.x >> 6;
    const int lane = threadIdx.x & 63;
    #pragma unroll
    for (int t = 0; t < 2; ++t) {
        const int idx = blockIdx.x * 8 + wave * 2 + t;   // i-row; partner idx+N
        float2 vi = *(const float2*)(zi + (size_t)idx * DIM + lane * 2);
        float2 vj = *(const float2*)(zj + (size_t)idx * DIM + lane * 2);
        float ssi = vi.x * vi.x + vi.y * vi.y;
        float ssj = vj.x * vj.x + vj.y * vj.y;
        float cr  = vi.x * vj.x + vi.y * vj.y;
        #pragma unroll
        for (int m = 32; m >= 1; m >>= 1) {
            ssi += __shfl_xor(ssi, m, 64);
            ssj += __shfl_xor(ssj, m, 64);
            cr  += __shfl_xor(cr,  m, 64);
        }
        const float sci = 1.0f / fmaxf(sqrtf(ssi), 1e-8f);
        const float scj = 1.0f / fmaxf(sqrtf(ssj), 1e-8f);
        bf16x2 a, b;
        a[0] = (__bf16)(vi.x * sci);      a[1] = (__bf16)(vi.y * sci);
        b[0] = (__bf16)(vi.x * sci * C1); b[1] = (__bf16)(vi.y * sci * C1);
        *(bf16x2*)(rn  + (size_t)idx * ROW_BYTES + lane * 4) = a;
        *(bf16x2*)(rnA + (size_t)idx * ROW_BYTES + lane * 4) = b;
        a[0] = (__bf16)(vj.x * scj);      a[1] = (__bf16)(vj.y * scj);
        b[0] = (__bf16)(vj.x * scj * C1); b[1] = (__bf16)(vj.y * scj * C1);
        *(bf16x2*)(rn  + (size_t)(idx + HALF_N) * ROW_BYTES + lane * 4) = a;
        *(bf16x2*)(rnA + (size_t)(idx + HALF_N) * ROW_BYTES + lane * 4) = b;
        if (lane == 0) {
            const float p = cr * sci * scj;
            pbuf[idx] = p;
            pbuf[idx + HALF_N] = p;
        }
    }
    if (threadIdx.x < 16) rowsum[blockIdx.x * 16 + threadIdx.x] = 0.0f;
    if (blockIdx.x == 0 && threadIdx.x == 0) *done = 0u;
}

// ---- kernel 2: wave-independent sim GEMM + exp rowsum + fused finalize -----
// R8's proven inner loop. __launch_bounds__(256,4): VGPR cap 128 so afrag
// stays in arch VGPRs (R9/R10: default bounds squeezed VGPR to 52/64 for
// 8-wave occupancy our 4-blocks/CU grid can't use -> operand-move stalls).
// NO producer-side __threadfence (R9/R10: per-block buffer_wbl2 + ACQ_REL
// serialized at TCC; R8 without it was 2x faster). Correctness: rowsum flows
// through device-scope atomics; __syncthreads drains vmcnt before the
// relaxed done-increment; only the LAST block issues the acquire fence.
__global__ __launch_bounds__(256, 4) void k_gemm(
    const char* __restrict__ rn, const char* __restrict__ rnA,
    float* __restrict__ rowsum, const float* __restrict__ pbuf,
    unsigned int* __restrict__ done, float* __restrict__ out)
{
    const int wave = threadIdx.x >> 6;
    const int lane = threadIdx.x & 63;
    const int qrow = lane >> 4, lcol = lane & 15;
    const int cv = blockIdx.x & 31;                   // 32 col-splits of 256
    const int rg = (blockIdx.x >> 5) * 4 + wave;      // 128 row-groups of 64

    // A fragments: rows [rg*64,+64) from rnA (pre-scaled by C1), all K
    const char* Ab = rnA + (size_t)(rg * 64) * ROW_BYTES;
    bf16x8 afrag[4][4];
    #pragma unroll
    for (int mi = 0; mi < 4; ++mi)
        #pragma unroll
        for (int ks = 0; ks < 4; ++ks)
            afrag[mi][ks] = *(const bf16x8*)(Ab + (mi * 16 + lcol) * ROW_BYTES
                                             + ks * 64 + qrow * 16);

    float rsum[4][4];
    #pragma unroll
    for (int mi = 0; mi < 4; ++mi)
        #pragma unroll
        for (int r = 0; r < 4; ++r) rsum[mi][r] = 0.0f;

    const char* Bb = rn + (size_t)(cv * 256) * ROW_BYTES + lcol * ROW_BYTES + qrow * 16;

    #pragma unroll 1
    for (int s = 0; s < 16; ++s) {                    // 16 steps of 16 cols
        const char* bp = Bb + (size_t)s * 16 * ROW_BYTES;
        bf16x8 bfrag[4];
        #pragma unroll
        for (int ks = 0; ks < 4; ++ks)
            bfrag[ks] = *(const bf16x8*)(bp + ks * 64);

        f32x4 acc[4];
        const f32x4 zero = {0.0f, 0.0f, 0.0f, 0.0f};
        #pragma unroll
        for (int mi = 0; mi < 4; ++mi) acc[mi] = zero;
        #pragma unroll
        for (int ks = 0; ks < 4; ++ks)
            #pragma unroll
            for (int mi = 0; mi < 4; ++mi)
                acc[mi] = __builtin_amdgcn_mfma_f32_16x16x32_bf16(
                    afrag[mi][ks], bfrag[ks], acc[mi], 0, 0, 0);

        // rowsum += 2^(s*C1); acc already holds s*C1 via pre-scaled A
        #pragma unroll
        for (int mi = 0; mi < 4; ++mi)
            #pragma unroll
            for (int r = 0; r < 4; ++r)
                rsum[mi][r] += __builtin_amdgcn_exp2f(acc[mi][r]);
    }

    // reduce over the 16 col-lanes, one atomic per row
    #pragma unroll
    for (int mi = 0; mi < 4; ++mi)
        #pragma unroll
        for (int r = 0; r < 4; ++r) {
            float v = rsum[mi][r];
            v += __shfl_xor(v, 1, 64);
            v += __shfl_xor(v, 2, 64);
            v += __shfl_xor(v, 4, 64);
            v += __shfl_xor(v, 8, 64);
            if (lcol == 0)
                atomicAdd(&rowsum[rg * 64 + mi * 16 + qrow * 4 + r], v);
        }

    // ---- last-block finalize; NO producer-side fence ----
    __syncthreads();            // compiler drains vmcnt(0) before s_barrier
    __shared__ int is_last;
    if (threadIdx.x == 0) {
        unsigned old = __hip_atomic_fetch_add(done, 1u, __ATOMIC_RELAXED,
                                              __HIP_MEMORY_SCOPE_AGENT);
        is_last = (old == GBLK - 1);
    }
    __syncthreads();
    if (!is_last) return;
    __threadfence();            // acquire side only, once

    // loss_k = (log2(rowsum_k + 2^(p*C1)) - p*C1) * ln2   [v_log_f32 is LOG2]
    float lsum = 0.0f;
    for (int r = threadIdx.x; r < NROWS; r += 256) {
        float rs = __hip_atomic_load(&rowsum[r], __ATOMIC_RELAXED, __HIP_MEMORY_SCOPE_AGENT);
        float pc = pbuf[r] * C1;
        float S  = rs + __builtin_amdgcn_exp2f(pc);
        lsum += (__builtin_amdgcn_logf(S) - pc) * LN2;
    }
    #pragma unroll
    for (int m = 32; m >= 1; m >>= 1) lsum += __shfl_xor(lsum, m, 64);
    __shared__ float part[4];
    if (lane == 0) part[wave] = lsum;
    __syncthreads();
    if (threadIdx.x == 0)
        out[0] = (part[0] + part[1] + part[2] + part[3]) * (1.0f / (float)NROWS);
}

extern "C" void kernel_launch(void* const* d_in, const int* in_sizes, int n_in,
                              void* d_out, int out_size, void* d_ws, size_t ws_size,
                              hipStream_t stream)
{
    const float* zi = (const float*)d_in[0];
    const float* zj = (const float*)d_in[1];
    float* out = (float*)d_out;

    // ws: rn 2MB | rnA 2MB | rowsum f32[8192] | pbuf f32[8192] | done
    char*  rn     = (char*)d_ws;
    char*  rnA    = rn + (size_t)NROWS * ROW_BYTES;
    float* rowsum = (float*)(rnA + (size_t)NROWS * ROW_BYTES);
    float* pbuf   = rowsum + NROWS;
    unsigned int* done = (unsigned int*)(pbuf + NROWS);

    k_normalize<<<NROWS / 16, 256, 0, stream>>>(zi, zj, rn, rnA, rowsum, pbuf, done);
    k_gemm<<<GBLK, 256, 0, stream>>>(rn, rnA, rowsum, pbuf, done, out);
}

// Round 12
// 99.602 us; speedup vs baseline: 1.5177x; 1.1717x over previous
//
#include <hip/hip_runtime.h>
#include <hip/hip_bf16.h>

typedef __bf16 bf16x8 __attribute__((ext_vector_type(8)));
typedef __bf16 bf16x2 __attribute__((ext_vector_type(2)));
typedef float f32x4 __attribute__((ext_vector_type(4)));

#define NROWS 8192
#define HALF_N 4096
#define DIM 128
#define C1 14.42695040888963f    /* (1/T) * log2(e) */
#define LN2 0.6931471805599453f
#define GBLK 1024                /* 32 row-groups x 32 col-splits */

/* Packed MFMA-operand layout ("fragment order"): rows in groups of 16; each
   4096-B group g holds rows [g*16, g*16+16). Within a group: 4 ks-regions of
   1024 B; byte position lane*16 of ks-region holds chunk (ks*4 + (lane>>4))
   [16 B] of row (g*16 + (lane&15)). A wave's bfrag/afrag load is then ONE
   fully-coalesced 1 KB global_load_dwordx4 (R11: the unpacked version
   scattered 16 cache lines per load and serialized in the TA -> 60 us). */

// ---- kernel 1: normalize (i,j) pairs -> packA(=rn*C1), packB(=rn); p_k ----
__global__ __launch_bounds__(256) void k_normalize(
    const float* __restrict__ zi, const float* __restrict__ zj,
    char* __restrict__ packA, char* __restrict__ packB,
    float* __restrict__ rowsum, float* __restrict__ pbuf,
    unsigned int* __restrict__ done)
{
    const int wave = threadIdx.x >> 6;
    const int lane = threadIdx.x & 63;
    // dest offset of this lane's 4 bytes within a row's packed image:
    // ks = lane>>4, qrow = (lane>>2)&3, byte (lane&3)*4
    const int ks_  = lane >> 4;
    const int qr_  = (lane >> 2) & 3;
    const int rem_ = (lane & 3) * 4;
    #pragma unroll
    for (int t = 0; t < 2; ++t) {
        const int idx = blockIdx.x * 8 + wave * 2 + t;   // i-row; partner idx+N
        float2 vi = *(const float2*)(zi + (size_t)idx * DIM + lane * 2);
        float2 vj = *(const float2*)(zj + (size_t)idx * DIM + lane * 2);
        float ssi = vi.x * vi.x + vi.y * vi.y;
        float ssj = vj.x * vj.x + vj.y * vj.y;
        float cr  = vi.x * vj.x + vi.y * vj.y;
        #pragma unroll
        for (int m = 32; m >= 1; m >>= 1) {
            ssi += __shfl_xor(ssi, m, 64);
            ssj += __shfl_xor(ssj, m, 64);
            cr  += __shfl_xor(cr,  m, 64);
        }
        const float sci = 1.0f / fmaxf(sqrtf(ssi), 1e-8f);
        const float scj = 1.0f / fmaxf(sqrtf(ssj), 1e-8f);
        #pragma unroll
        for (int h = 0; h < 2; ++h) {                 // h=0: i-row, h=1: j-row
            const int   row = idx + h * HALF_N;
            const float sx  = h ? vj.x * scj : vi.x * sci;
            const float sy  = h ? vj.y * scj : vi.y * sci;
            const size_t off = (size_t)(row >> 4) * 4096 + ks_ * 1024
                             + (qr_ * 16 + (row & 15)) * 16 + rem_;
            bf16x2 a, b;
            a[0] = (__bf16)(sx * C1); a[1] = (__bf16)(sy * C1);
            b[0] = (__bf16)sx;        b[1] = (__bf16)sy;
            *(bf16x2*)(packA + off) = a;
            *(bf16x2*)(packB + off) = b;
        }
        if (lane == 0) {
            const float p = cr * sci * scj;
            pbuf[idx] = p;
            pbuf[idx + HALF_N] = p;
        }
    }
    if (threadIdx.x < 16) rowsum[blockIdx.x * 16 + threadIdx.x] = 0.0f;
    if (blockIdx.x == 0 && threadIdx.x == 0) *done = 0u;
}

// ---- kernel 2: wave-independent sim GEMM + exp rowsum + fused finalize -----
// R8/R11 proven structure; ALL loads now 1 KB coalesced from packed layout.
// No producer-side fences (R11-validated); last block finalizes.
__global__ __launch_bounds__(256, 4) void k_gemm(
    const char* __restrict__ packA, const char* __restrict__ packB,
    float* __restrict__ rowsum, const float* __restrict__ pbuf,
    unsigned int* __restrict__ done, float* __restrict__ out)
{
    const int wave = threadIdx.x >> 6;
    const int lane = threadIdx.x & 63;
    const int qrow = lane >> 4, lcol = lane & 15;
    const int cv = blockIdx.x & 31;                   // 32 col-splits of 256
    const int rg = (blockIdx.x >> 5) * 4 + wave;      // 128 row-groups of 64

    // A fragments: row-groups rg*4+mi, coalesced 1 KB loads
    bf16x8 afrag[4][4];
    #pragma unroll
    for (int mi = 0; mi < 4; ++mi)
        #pragma unroll
        for (int ks = 0; ks < 4; ++ks)
            afrag[mi][ks] = *(const bf16x8*)(packA
                + (size_t)(rg * 4 + mi) * 4096 + ks * 1024 + lane * 16);

    float rsum[4][4];
    #pragma unroll
    for (int mi = 0; mi < 4; ++mi)
        #pragma unroll
        for (int r = 0; r < 4; ++r) rsum[mi][r] = 0.0f;

    const char* Bb = packB + (size_t)(cv * 16) * 4096 + lane * 16;

    #pragma unroll 1
    for (int s = 0; s < 16; ++s) {                    // 16 steps of 16 cols
        const char* bp = Bb + (size_t)s * 4096;
        bf16x8 bfrag[4];
        #pragma unroll
        for (int ks = 0; ks < 4; ++ks)
            bfrag[ks] = *(const bf16x8*)(bp + ks * 1024);

        f32x4 acc[4];
        const f32x4 zero = {0.0f, 0.0f, 0.0f, 0.0f};
        #pragma unroll
        for (int mi = 0; mi < 4; ++mi) acc[mi] = zero;
        #pragma unroll
        for (int ks = 0; ks < 4; ++ks)
            #pragma unroll
            for (int mi = 0; mi < 4; ++mi)
                acc[mi] = __builtin_amdgcn_mfma_f32_16x16x32_bf16(
                    afrag[mi][ks], bfrag[ks], acc[mi], 0, 0, 0);

        // rowsum += 2^(s*C1); acc already holds s*C1 via pre-scaled A
        #pragma unroll
        for (int mi = 0; mi < 4; ++mi)
            #pragma unroll
            for (int r = 0; r < 4; ++r)
                rsum[mi][r] += __builtin_amdgcn_exp2f(acc[mi][r]);
    }

    // reduce over the 16 col-lanes, one atomic per row
    #pragma unroll
    for (int mi = 0; mi < 4; ++mi)
        #pragma unroll
        for (int r = 0; r < 4; ++r) {
            float v = rsum[mi][r];
            v += __shfl_xor(v, 1, 64);
            v += __shfl_xor(v, 2, 64);
            v += __shfl_xor(v, 4, 64);
            v += __shfl_xor(v, 8, 64);
            if (lcol == 0)
                atomicAdd(&rowsum[rg * 64 + mi * 16 + qrow * 4 + r], v);
        }

    // ---- last-block finalize; no producer-side fence (R11-validated) ----
    __syncthreads();            // compiler drains vmcnt(0) before s_barrier
    __shared__ int is_last;
    if (threadIdx.x == 0) {
        unsigned old = __hip_atomic_fetch_add(done, 1u, __ATOMIC_RELAXED,
                                              __HIP_MEMORY_SCOPE_AGENT);
        is_last = (old == GBLK - 1);
    }
    __syncthreads();
    if (!is_last) return;
    __threadfence();            // acquire side only, once

    // loss_k = (log2(rowsum_k + 2^(p*C1)) - p*C1) * ln2   [v_log_f32 is LOG2]
    float lsum = 0.0f;
    for (int r = threadIdx.x; r < NROWS; r += 256) {
        float rs = __hip_atomic_load(&rowsum[r], __ATOMIC_RELAXED, __HIP_MEMORY_SCOPE_AGENT);
        float pc = pbuf[r] * C1;
        float S  = rs + __builtin_amdgcn_exp2f(pc);
        lsum += (__builtin_amdgcn_logf(S) - pc) * LN2;
    }
    #pragma unroll
    for (int m = 32; m >= 1; m >>= 1) lsum += __shfl_xor(lsum, m, 64);
    __shared__ float part[4];
    if (lane == 0) part[wave] = lsum;
    __syncthreads();
    if (threadIdx.x == 0)
        out[0] = (part[0] + part[1] + part[2] + part[3]) * (1.0f / (float)NROWS);
}

extern "C" void kernel_launch(void* const* d_in, const int* in_sizes, int n_in,
                              void* d_out, int out_size, void* d_ws, size_t ws_size,
                              hipStream_t stream)
{
    const float* zi = (const float*)d_in[0];
    const float* zj = (const float*)d_in[1];
    float* out = (float*)d_out;

    // ws: packA 2MB | packB 2MB | rowsum f32[8192] | pbuf f32[8192] | done
    char*  packA  = (char*)d_ws;
    char*  packB  = packA + (size_t)NROWS * 256;
    float* rowsum = (float*)(packB + (size_t)NROWS * 256);
    float* pbuf   = rowsum + NROWS;
    unsigned int* done = (unsigned int*)(pbuf + NROWS);

    k_normalize<<<NROWS / 16, 256, 0, stream>>>(zi, zj, packA, packB, rowsum, pbuf, done);
    k_gemm<<<GBLK, 256, 0, stream>>>(packA, packB, rowsum, pbuf, done, out);
}